// Round 7
// baseline (114.409 us; speedup 1.0000x reference)
//
#include <hip/hip_runtime.h>

// WaveletLinear: y[b,o] = sum_i w[o,i] * (1 - s^2) * exp(-0.5 s^2),
//   s = (x[b,i] - t[o,i]) / (A_MIN + softplus(sr[o,i]) + EPS)
// Rework: u = K*s'^2 with s' = s*sqrt(K), K = 0.5*log2(e); e2 = exp2(-u);
//   y = sum_i (mwk*u + w) * e2,  mwk = -w/K     <- single-accumulator form
//
// R12: R11 + ping-pong register prefetch of params, in PLAIN C (R9's asm
// attempt broke; this is the same schedule with compiler-managed waits).
// Evidence: R11 wall ~440 cyc/step-slot vs ~190 issue model; occupancy is
// at the thread cap, VALU work at the 13.7us floor -> remaining ~18us idle
// is load->use distance ~0 at unroll-group tops (all 8 waves/SIMD phase-
// locked, correlated L2 stalls). Fix: load group g+1's 12 param dwords into
// the spare buffer while computing group g (distance = 4 steps ~ 480 cyc of
// compute vs ~200-400 cyc L2 latency). Fully unrolled -> static indices ->
// registers (rule #20). Everything else byte-identical to R11.

#define WL_A_MIN 0.001f
#define WL_EPS   1e-8f

constexpr int WL_B = 512;
constexpr int WL_O = 1024;
constexpr int WL_I = 512;

// K = 0.5*log2(e); sqrt(K); 1/K; log2(e); ln(2)
#define WL_SQK  0.84932180553704583800f
#define WL_IK   1.38629436111989061883f
#define WL_L2E  1.44269504088896340736f
#define WL_LN2  0.69314718055994530942f

typedef float v2f __attribute__((ext_vector_type(2)));

struct P3 { float nti, inv, w; };          // prep-internal LDS staging

__device__ __forceinline__ float fast_exp2(float a) {
#if __has_builtin(__builtin_amdgcn_exp2f)
    return __builtin_amdgcn_exp2f(a);
#else
    return exp2f(a);
#endif
}
__device__ __forceinline__ float fast_log2(float a) {
#if __has_builtin(__builtin_amdgcn_logf)
    return __builtin_amdgcn_logf(a);
#else
    return __log2f(a);
#endif
}
__device__ __forceinline__ float fast_rcp(float a) {
#if __has_builtin(__builtin_amdgcn_rcpf)
    return __builtin_amdgcn_rcpf(a);
#else
    return 1.0f / a;
#endif
}

// Param precompute (UNCHANGED, verified). Block = 256 thr handles a
// 64(o) x 16(i) tile. Phase 1: coalesced float4 reads, compute, store P3 to
// LDS (transpose). Phase 2: lane=o writes A2[i][o]={nti,inv}, W1[i][o]=w.
__global__ __launch_bounds__(256) void wl_prep(
    const float* __restrict__ translation,
    const float* __restrict__ scale_raw,
    const float* __restrict__ weights,
    v2f* __restrict__ A2,
    float* __restrict__ W1)
{
    __shared__ P3 lds[16 * 64];                        // 12 KB  [i_l][o_l]
    const int t  = threadIdx.x;
    const int o0 = blockIdx.x * 64;
    const int i0 = blockIdx.y * 16;

    {
        const int o_l = t >> 2;                        // 0..63
        const int iq  = t & 3;                         // 0..3 -> 4 i each
        const size_t g = (size_t)(o0 + o_l) * WL_I + (i0 + iq * 4);
        const float4 tv = *reinterpret_cast<const float4*>(translation + g);
        const float4 sv = *reinterpret_cast<const float4*>(scale_raw   + g);
        const float4 wv = *reinterpret_cast<const float4*>(weights     + g);
        const float tt[4] = {tv.x, tv.y, tv.z, tv.w};
        const float ss[4] = {sv.x, sv.y, sv.z, sv.w};
        const float ww[4] = {wv.x, wv.y, wv.z, wv.w};
        #pragma unroll
        for (int j = 0; j < 4; ++j) {
            float ex  = fast_exp2(ss[j] * WL_L2E);     // softplus via hw exp2/log2
            float sp  = fast_log2(1.0f + ex) * WL_LN2;
            float inv = fast_rcp(WL_A_MIN + sp + WL_EPS) * WL_SQK;
            P3 pv; pv.nti = -tt[j] * inv; pv.inv = inv; pv.w = ww[j];
            lds[(iq * 4 + j) * 64 + o_l] = pv;
        }
    }
    __syncthreads();
    {
        const int o_l = t & 63;
        const int r   = t >> 6;                        // 0..3 -> 4 i each
        const int o   = o0 + o_l;
        #pragma unroll
        for (int j = 0; j < 4; ++j) {
            const int i_l = r * 4 + j;
            P3 a = lds[i_l * 64 + o_l];
            A2[(size_t)(i0 + i_l) * WL_O + o] = (v2f){a.nti, a.inv};
            W1[(size_t)(i0 + i_l) * WL_O + o] = a.w;
        }
    }
}

// Main: grid (O/64=16, B/16=32) = 512 blocks (2/CU), 1024 thr = 16 waves.
// Wave wid = i-sixteenth (32 i = 8 groups of 4); covers all 16 b of the tile.
// XCD = gx mod 8 -> 2 param slabs per XCD's L2 (786 KB, resident).
__global__ __launch_bounds__(1024, 8) void wl_main(
    const float* __restrict__ x,
    const v2f* __restrict__ A2,
    const float* __restrict__ W1,
    float* __restrict__ out)
{
    __shared__ float smem[8192];                       // 32 KB: xT, then reduce

    const int tid  = threadIdx.x;
    const int lane = tid & 63;
    const int wid  = tid >> 6;                         // 0..15 = i-sixteenth
    const int o    = blockIdx.x * 64 + lane;
    const int b0   = blockIdx.y * 16;

    // ---- stage x^T once: xT[i*16 + b_l]; 4-way write conflicts, one-time ----
    {
        const int b_l = tid & 15;
        const int seg = tid >> 4;                      // 0..63 -> i in [seg*8,+8)
        const float* xg = &x[(size_t)(b0 + b_l) * WL_I + seg * 8];
        const float4 v0 = *reinterpret_cast<const float4*>(xg);
        const float4 v1 = *reinterpret_cast<const float4*>(xg + 4);
        const int base = seg * 8 * 16 + b_l;
        smem[base + 0 * 16] = v0.x;
        smem[base + 1 * 16] = v0.y;
        smem[base + 2 * 16] = v0.z;
        smem[base + 3 * 16] = v0.w;
        smem[base + 4 * 16] = v1.x;
        smem[base + 5 * 16] = v1.y;
        smem[base + 6 * 16] = v1.z;
        smem[base + 7 * 16] = v1.w;
    }
    __syncthreads();

    const v2f*   __restrict__ pA = A2 + (size_t)(wid * 32) * WL_O + o;
    const float* __restrict__ pW = W1 + (size_t)(wid * 32) * WL_O + o;
    const float* xrow = &smem[wid * 32 * 16];          // uniform per wave

    float acc[16] = {0.f,0.f,0.f,0.f, 0.f,0.f,0.f,0.f,
                     0.f,0.f,0.f,0.f, 0.f,0.f,0.f,0.f};

    // ---- ping-pong prefetched main loop: 8 groups of 4 i-steps ----
    v2f   pab[2][4];                                   // param double buffer
    float wb [2][4];

    #pragma unroll
    for (int k = 0; k < 4; ++k) {                      // preload group 0
        pab[0][k] = pA[(size_t)k * WL_O];
        wb [0][k] = pW[(size_t)k * WL_O];
    }

    #pragma unroll
    for (int g = 0; g < 8; ++g) {
        const int cur = g & 1, nxt = cur ^ 1;          // compile-time (full unroll)
        if (g < 7) {                                   // prefetch group g+1
            #pragma unroll
            for (int k = 0; k < 4; ++k) {
                pab[nxt][k] = pA[(size_t)((g + 1) * 4 + k) * WL_O];
                wb [nxt][k] = pW[(size_t)((g + 1) * 4 + k) * WL_O];
            }
        }
        #pragma unroll
        for (int k = 0; k < 4; ++k) {                  // compute group g
            const int ii = g * 4 + k;
            const v2f   pa  = pab[cur][k];
            const float w   = wb [cur][k];
            const float mwk = w * (-WL_IK);
            const float nti = pa.x, inv = pa.y;
            const float4* xf = reinterpret_cast<const float4*>(xrow + ii * 16);
            #pragma unroll
            for (int q = 0; q < 4; ++q) {
                const float4 xq = xf[q];               // uniform LDS broadcast
                const float xs[4] = {xq.x, xq.y, xq.z, xq.w};
                #pragma unroll
                for (int j = 0; j < 4; ++j) {
                    const int b = q * 4 + j;
                    const float s = fmaf(xs[j], inv, nti);
                    const float u = s * s;
                    const float e = fast_exp2(-u);     // neg folds into trans src-mod
                    const float v = fmaf(mwk, u, w);
                    acc[b] = fmaf(v, e, acc[b]);
                }
            }
        }
    }

    // ---- reduce over 16 i-waves: two phases of 8 b each ----
    __syncthreads();                                   // done reading xT
    #pragma unroll
    for (int k = 0; k < 8; ++k)                        // dump acc[0..7] (b_l 0..7)
        smem[(wid * 8 + k) * 64 + lane] = acc[k];      // lane-stride 4B: conflict-free
    __syncthreads();
    if (wid < 8) {                                     // wave w sums b_l = w
        float y = 0.f;
        #pragma unroll
        for (int src = 0; src < 16; ++src)
            y += smem[(src * 8 + wid) * 64 + lane];
        out[(size_t)(b0 + wid) * WL_O + o] = y;
    }
    __syncthreads();
    #pragma unroll
    for (int k = 0; k < 8; ++k)                        // dump acc[8..15] (b_l 8..15)
        smem[(wid * 8 + k) * 64 + lane] = acc[8 + k];
    __syncthreads();
    if (wid >= 8) {                                    // wave w sums b_l = w
        float y = 0.f;
        #pragma unroll
        for (int src = 0; src < 16; ++src)
            y += smem[(src * 8 + (wid - 8)) * 64 + lane];
        out[(size_t)(b0 + wid) * WL_O + o] = y;
    }
}

extern "C" void kernel_launch(void* const* d_in, const int* in_sizes, int n_in,
                              void* d_out, int out_size, void* d_ws, size_t ws_size,
                              hipStream_t stream) {
    const float* x           = (const float*)d_in[0];
    const float* translation = (const float*)d_in[1];
    const float* scale_raw   = (const float*)d_in[2];
    const float* weights     = (const float*)d_in[3];
    float*       out         = (float*)d_out;
    // workspace: A2 pairs {nti,inv} 4.19MB, then W1 floats 2.10MB (6.3MB total)
    v2f*   A2 = (v2f*)d_ws;
    float* W1 = (float*)((char*)d_ws + (size_t)WL_I * WL_O * sizeof(v2f));

    wl_prep<<<dim3(WL_O / 64, WL_I / 16), dim3(256), 0, stream>>>(
        translation, scale_raw, weights, A2, W1);

    wl_main<<<dim3(WL_O / 64, WL_B / 16), dim3(1024), 0, stream>>>(
        x, A2, W1, out);
}

// Round 8
// 104.992 us; speedup vs baseline: 1.0897x; 1.0897x over previous
//
#include <hip/hip_runtime.h>

// WaveletLinear: y[b,o] = sum_i w[o,i] * (1 - s^2) * exp(-0.5 s^2),
//   s = (x[b,i] - t[o,i]) / (A_MIN + softplus(sr[o,i]) + EPS)
// Rework: u = K*s'^2 with s' = s*sqrt(K), K = 0.5*log2(e); e2 = exp2(-u);
//   y = sum_i (mwk*u + w) * e2,  mwk = -w/K     <- single-accumulator form
//
// R13: R11 + depth-2 param prefetch in NAMED SCALARS. R12's array-based
// ping-pong went to scratch (WRITE_SIZE 2->16MB = rule-#20 violation) and
// regressed; the schedule itself was never tested. This version keeps the
// rotation in named regs (paC/paN/paF), no arrays, no asm -> no scratch
// possible. Load for step ii+2 issues ~512 busy-cyc ahead of use (covers
// L2 latency ~200-400). Everything else byte-identical to R11 (47.4us,
// VGPR 28, the best verified kernel).
// Verification targets: WRITE_SIZE == 2048 KB (no scratch), VGPR 40-48.

#define WL_A_MIN 0.001f
#define WL_EPS   1e-8f

constexpr int WL_B = 512;
constexpr int WL_O = 1024;
constexpr int WL_I = 512;

// K = 0.5*log2(e); sqrt(K); 1/K; log2(e); ln(2)
#define WL_SQK  0.84932180553704583800f
#define WL_IK   1.38629436111989061883f
#define WL_L2E  1.44269504088896340736f
#define WL_LN2  0.69314718055994530942f

typedef float v2f __attribute__((ext_vector_type(2)));

struct P3 { float nti, inv, w; };          // prep-internal LDS staging

__device__ __forceinline__ float fast_exp2(float a) {
#if __has_builtin(__builtin_amdgcn_exp2f)
    return __builtin_amdgcn_exp2f(a);
#else
    return exp2f(a);
#endif
}
__device__ __forceinline__ float fast_log2(float a) {
#if __has_builtin(__builtin_amdgcn_logf)
    return __builtin_amdgcn_logf(a);
#else
    return __log2f(a);
#endif
}
__device__ __forceinline__ float fast_rcp(float a) {
#if __has_builtin(__builtin_amdgcn_rcpf)
    return __builtin_amdgcn_rcpf(a);
#else
    return 1.0f / a;
#endif
}

// one i-step over 16 b: 64 VALU + 16 trans (verified R11 body)
__device__ __forceinline__ void wl_step16(const v2f pa, const float w,
                                          const float* xrow, float* acc) {
    const float mwk = w * (-WL_IK);
    const float nti = pa.x, inv = pa.y;
    const float4* xf = reinterpret_cast<const float4*>(xrow);
    #pragma unroll
    for (int q = 0; q < 4; ++q) {
        const float4 xq = xf[q];                       // uniform LDS broadcast
        const float xs[4] = {xq.x, xq.y, xq.z, xq.w};
        #pragma unroll
        for (int j = 0; j < 4; ++j) {
            const int b = q * 4 + j;
            const float s = fmaf(xs[j], inv, nti);
            const float u = s * s;
            const float e = fast_exp2(-u);             // neg folds into trans src-mod
            const float v = fmaf(mwk, u, w);
            acc[b] = fmaf(v, e, acc[b]);
        }
    }
}

// Param precompute (UNCHANGED, verified). Block = 256 thr handles a
// 64(o) x 16(i) tile. Phase 1: coalesced float4 reads, compute, store P3 to
// LDS (transpose). Phase 2: lane=o writes A2[i][o]={nti,inv}, W1[i][o]=w.
__global__ __launch_bounds__(256) void wl_prep(
    const float* __restrict__ translation,
    const float* __restrict__ scale_raw,
    const float* __restrict__ weights,
    v2f* __restrict__ A2,
    float* __restrict__ W1)
{
    __shared__ P3 lds[16 * 64];                        // 12 KB  [i_l][o_l]
    const int t  = threadIdx.x;
    const int o0 = blockIdx.x * 64;
    const int i0 = blockIdx.y * 16;

    {
        const int o_l = t >> 2;                        // 0..63
        const int iq  = t & 3;                         // 0..3 -> 4 i each
        const size_t g = (size_t)(o0 + o_l) * WL_I + (i0 + iq * 4);
        const float4 tv = *reinterpret_cast<const float4*>(translation + g);
        const float4 sv = *reinterpret_cast<const float4*>(scale_raw   + g);
        const float4 wv = *reinterpret_cast<const float4*>(weights     + g);
        const float tt[4] = {tv.x, tv.y, tv.z, tv.w};
        const float ss[4] = {sv.x, sv.y, sv.z, sv.w};
        const float ww[4] = {wv.x, wv.y, wv.z, wv.w};
        #pragma unroll
        for (int j = 0; j < 4; ++j) {
            float ex  = fast_exp2(ss[j] * WL_L2E);     // softplus via hw exp2/log2
            float sp  = fast_log2(1.0f + ex) * WL_LN2;
            float inv = fast_rcp(WL_A_MIN + sp + WL_EPS) * WL_SQK;
            P3 pv; pv.nti = -tt[j] * inv; pv.inv = inv; pv.w = ww[j];
            lds[(iq * 4 + j) * 64 + o_l] = pv;
        }
    }
    __syncthreads();
    {
        const int o_l = t & 63;
        const int r   = t >> 6;                        // 0..3 -> 4 i each
        const int o   = o0 + o_l;
        #pragma unroll
        for (int j = 0; j < 4; ++j) {
            const int i_l = r * 4 + j;
            P3 a = lds[i_l * 64 + o_l];
            A2[(size_t)(i0 + i_l) * WL_O + o] = (v2f){a.nti, a.inv};
            W1[(size_t)(i0 + i_l) * WL_O + o] = a.w;
        }
    }
}

// Main: grid (O/64=16, B/16=32) = 512 blocks (2/CU), 1024 thr = 16 waves.
// Wave wid = i-sixteenth (32 i); covers all 16 b of the tile.
// XCD = gx mod 8 -> 2 param slabs per XCD's L2 (786 KB, resident).
__global__ __launch_bounds__(1024, 8) void wl_main(
    const float* __restrict__ x,
    const v2f* __restrict__ A2,
    const float* __restrict__ W1,
    float* __restrict__ out)
{
    __shared__ float smem[8192];                       // 32 KB: xT, then reduce

    const int tid  = threadIdx.x;
    const int lane = tid & 63;
    const int wid  = tid >> 6;                         // 0..15 = i-sixteenth
    const int o    = blockIdx.x * 64 + lane;
    const int b0   = blockIdx.y * 16;

    // ---- stage x^T once: xT[i*16 + b_l]; 4-way write conflicts, one-time ----
    {
        const int b_l = tid & 15;
        const int seg = tid >> 4;                      // 0..63 -> i in [seg*8,+8)
        const float* xg = &x[(size_t)(b0 + b_l) * WL_I + seg * 8];
        const float4 v0 = *reinterpret_cast<const float4*>(xg);
        const float4 v1 = *reinterpret_cast<const float4*>(xg + 4);
        const int base = seg * 8 * 16 + b_l;
        smem[base + 0 * 16] = v0.x;
        smem[base + 1 * 16] = v0.y;
        smem[base + 2 * 16] = v0.z;
        smem[base + 3 * 16] = v0.w;
        smem[base + 4 * 16] = v1.x;
        smem[base + 5 * 16] = v1.y;
        smem[base + 6 * 16] = v1.z;
        smem[base + 7 * 16] = v1.w;
    }
    __syncthreads();

    const v2f*   __restrict__ pA = A2 + (size_t)(wid * 32) * WL_O + o;
    const float* __restrict__ pW = W1 + (size_t)(wid * 32) * WL_O + o;
    const float* xrow = &smem[wid * 32 * 16];          // uniform per wave

    float acc[16] = {0.f,0.f,0.f,0.f, 0.f,0.f,0.f,0.f,
                     0.f,0.f,0.f,0.f, 0.f,0.f,0.f,0.f};

    // ---- depth-2 software pipeline on params, NAMED SCALARS only ----
    v2f   paC = pA[0];       float wC = pW[0];
    v2f   paN = pA[WL_O];    float wN = pW[WL_O];

    #pragma unroll 4
    for (int ii = 0; ii < 30; ++ii) {
        const v2f   paF = pA[(size_t)(ii + 2) * WL_O]; // prefetch step ii+2
        const float wF  = pW[(size_t)(ii + 2) * WL_O];
        wl_step16(paC, wC, xrow + ii * 16, acc);       // compute step ii
        paC = paN;  wC = wN;                           // rotate (reg moves)
        paN = paF;  wN = wF;
    }
    wl_step16(paC, wC, xrow + 30 * 16, acc);           // epilogue: steps 30,31
    wl_step16(paN, wN, xrow + 31 * 16, acc);

    // ---- reduce over 16 i-waves: two phases of 8 b each ----
    __syncthreads();                                   // done reading xT
    #pragma unroll
    for (int k = 0; k < 8; ++k)                        // dump acc[0..7] (b_l 0..7)
        smem[(wid * 8 + k) * 64 + lane] = acc[k];      // lane-stride 4B: conflict-free
    __syncthreads();
    if (wid < 8) {                                     // wave w sums b_l = w
        float y = 0.f;
        #pragma unroll
        for (int src = 0; src < 16; ++src)
            y += smem[(src * 8 + wid) * 64 + lane];
        out[(size_t)(b0 + wid) * WL_O + o] = y;
    }
    __syncthreads();
    #pragma unroll
    for (int k = 0; k < 8; ++k)                        // dump acc[8..15] (b_l 8..15)
        smem[(wid * 8 + k) * 64 + lane] = acc[8 + k];
    __syncthreads();
    if (wid >= 8) {                                    // wave w sums b_l = w
        float y = 0.f;
        #pragma unroll
        for (int src = 0; src < 16; ++src)
            y += smem[(src * 8 + (wid - 8)) * 64 + lane];
        out[(size_t)(b0 + wid) * WL_O + o] = y;
    }
}

extern "C" void kernel_launch(void* const* d_in, const int* in_sizes, int n_in,
                              void* d_out, int out_size, void* d_ws, size_t ws_size,
                              hipStream_t stream) {
    const float* x           = (const float*)d_in[0];
    const float* translation = (const float*)d_in[1];
    const float* scale_raw   = (const float*)d_in[2];
    const float* weights     = (const float*)d_in[3];
    float*       out         = (float*)d_out;
    // workspace: A2 pairs {nti,inv} 4.19MB, then W1 floats 2.10MB (6.3MB total)
    v2f*   A2 = (v2f*)d_ws;
    float* W1 = (float*)((char*)d_ws + (size_t)WL_I * WL_O * sizeof(v2f));

    wl_prep<<<dim3(WL_O / 64, WL_I / 16), dim3(256), 0, stream>>>(
        translation, scale_raw, weights, A2, W1);

    wl_main<<<dim3(WL_O / 64, WL_B / 16), dim3(1024), 0, stream>>>(
        x, A2, W1, out);
}